// Round 4
// baseline (165076.062 us; speedup 1.0000x reference)
//
#include <hip/hip_runtime.h>
#include <math.h>

#define B_   64
#define T_   512
#define IN_  64
#define HID_ 256
#define KTOT 65536   // HID*HID

typedef __attribute__((ext_vector_type(8))) short  short8;
typedef __attribute__((ext_vector_type(4))) float  floatx4;

__device__ __forceinline__ unsigned short f2bf(float f) {
    unsigned int u = __float_as_uint(f);
    u += 0x7FFFu + ((u >> 16) & 1u);          // round-to-nearest-even
    return (unsigned short)(u >> 16);
}
__device__ __forceinline__ float bf2f(unsigned short s) {
    return __uint_as_float(((unsigned int)s) << 16);
}

// ---- once per launch: W_hh fp32 -> bf16 ----------------------------------
__global__ __launch_bounds__(256) void conv_w(const float* __restrict__ W,
                                              unsigned short* __restrict__ Wb)
{
    const size_t idx = ((size_t)blockIdx.x * 256 + threadIdx.x) * 4;
    const float4 v = *(const float4*)(W + idx);
    unsigned int lo = (unsigned int)f2bf(v.x) | ((unsigned int)f2bf(v.y) << 16);
    unsigned int hi = (unsigned int)f2bf(v.z) | ((unsigned int)f2bf(v.w) << 16);
    *(uint2*)(Wb + idx) = make_uint2(lo, hi);
}

// ---- init: rB(bf16) from x0, zero barrier counters -----------------------
__global__ __launch_bounds__(256) void init_rB(const float* __restrict__ x0,
                                               unsigned short* __restrict__ rB,
                                               unsigned int* __restrict__ bar)
{
    const int b = blockIdx.x;
    const int i = threadIdx.x;
    rB[b * HID_ + i] = f2bf(tanhf(x0[b * HID_ + i]));
    if (b == 0) { bar[i] = 0u; bar[i + 256] = 0u; }   // zero 512 uints
}

// Barrier word indices (each hot word on its own 128B line):
//   A_leaf[l] @ l*32 (l=0..7), A_root @ 256, A_gen @ 288, B_cnt @ 320, B_gen @ 352

// ---- persistent kernel: all 512 timesteps, manual grid barrier -----------
// grid = 512 blocks x 256 thr, 64 KB LDS, __launch_bounds__(256,2) -> VGPR<=256
// => HW occupancy 2 blocks/CU, all 512 blocks co-resident on 256 CUs.
// Block (ig=bid>>7, c=bid&127): i-range [ig*64,+64), k-slice [c*512,+512).
// W_hh slice staged to LDS ONCE. Per step:
//   gemm (all) -> arrive A -> [combine blocks: wait A, combine, arrive B]
//   -> all wait B.
__global__ __launch_bounds__(256, 2) void rnn_persistent(
    const unsigned short* __restrict__ Wb,
    unsigned short* __restrict__ rB,
    float* __restrict__ P,
    const float* __restrict__ u,
    const float* __restrict__ x0,
    const float* __restrict__ noise,
    const float* __restrict__ W_in,
    const float* __restrict__ b_in,
    float* __restrict__ traj,
    float* __restrict__ xf,
    unsigned int* __restrict__ bar)
{
    __shared__ unsigned short A_lds[32768];  // 64 KB: [itile(4)][kc(16)][lane(64)][8]

    const int tid = threadIdx.x;
    const int l   = tid & 63;
    const int w   = tid >> 6;        // wave 0..3
    const int m   = l & 15;
    const int q   = l >> 4;
    const int bid = blockIdx.x;
    const int ig  = bid >> 7;        // i-group 0..3
    const int c   = bid & 127;       // k-slice 0..127
    const int i0  = ig << 6;

    // ---- stage W slice to LDS once (persists across all steps) ----
    {
        const unsigned short* src = Wb + (size_t)(i0 + (w << 4) + m) * KTOT
                                       + (c << 9) + (q << 3);
        unsigned short* dst = &A_lds[(w << 13) + (l << 3)];
        #pragma unroll
        for (int kc = 0; kc < 16; ++kc) {
            *(uint4*)(dst + (kc << 9)) = *(const uint4*)(src + (kc << 5));
        }
    }
    __syncthreads();

    const int b = (w << 4) + m;                  // gemm: this lane's batch row
    const unsigned short* rrow_base = rB + b * HID_ + (q << 3);

    // ---- combine-phase register state (blocks 0..63 only) ----
    const bool is_cb = (bid < 64);
    float win[64];
    float bin = 0.f, xcur = 0.f;
    if (is_cb) {
        #pragma unroll
        for (int k = 0; k < 64; ++k) win[k] = W_in[tid * IN_ + k];  // W_in[i][k]
        bin  = b_in[tid];
        xcur = x0[bid * HID_ + tid];
    }

    unsigned int genA = 0, genB = 0;

    #pragma unroll 1
    for (int t = 0; t < T_; ++t) {
        // ================= gemm phase (all blocks) =================
        const float rj0 = bf2f(rB[b * HID_ + 2 * c]);
        const float rj1 = bf2f(rB[b * HID_ + 2 * c + 1]);

        floatx4 acc0 = {0.f, 0.f, 0.f, 0.f};
        floatx4 acc1 = {0.f, 0.f, 0.f, 0.f};
        floatx4 acc2 = {0.f, 0.f, 0.f, 0.f};
        floatx4 acc3 = {0.f, 0.f, 0.f, 0.f};

        #pragma unroll
        for (int kc = 0; kc < 16; ++kc) {
            const float rj = (kc < 8) ? rj0 : rj1;
            const uint4 rv = *(const uint4*)(rrow_base + ((kc & 7) << 5));
            short8 gfrag;
            {
                unsigned int* gp = (unsigned int*)&gfrag;
                const unsigned short* rs = (const unsigned short*)&rv;
                #pragma unroll
                for (int p = 0; p < 4; ++p) {
                    const float lo = bf2f(rs[2 * p])     * rj;
                    const float hi = bf2f(rs[2 * p + 1]) * rj;
                    gp[p] = (unsigned int)f2bf(lo) | ((unsigned int)f2bf(hi) << 16);
                }
            }
            const unsigned short* ab = &A_lds[(kc << 9) + (l << 3)];
            const short8 w0 = *(const short8*)(ab);
            const short8 w1 = *(const short8*)(ab + 8192);
            const short8 w2 = *(const short8*)(ab + 16384);
            const short8 w3 = *(const short8*)(ab + 24576);
            acc0 = __builtin_amdgcn_mfma_f32_16x16x32_bf16(gfrag, w0, acc0, 0, 0, 0);
            acc1 = __builtin_amdgcn_mfma_f32_16x16x32_bf16(gfrag, w1, acc1, 0, 0, 0);
            acc2 = __builtin_amdgcn_mfma_f32_16x16x32_bf16(gfrag, w2, acc2, 0, 0, 0);
            acc3 = __builtin_amdgcn_mfma_f32_16x16x32_bf16(gfrag, w3, acc3, 0, 0, 0);
        }

        // C layout: row(b_local) = q*4+reg, col(i_local) = m
        #pragma unroll
        for (int reg = 0; reg < 4; ++reg) {
            float* dst = P + (c << 14) + ((w << 4) + (q << 2) + reg) * HID_ + i0 + m;
            dst[0]  = acc0[reg];
            dst[16] = acc1[reg];
            dst[32] = acc2[reg];
            dst[48] = acc3[reg];
        }

        __syncthreads();                     // all P stores drained to L2
        if (tid == 0) {
            __threadfence();                 // release P (L2 writeback)
            const int leaf = (bid & 7) << 5;
            if (__hip_atomic_fetch_add(&bar[leaf], 1u, __ATOMIC_ACQ_REL,
                                       __HIP_MEMORY_SCOPE_AGENT) == 63u) {
                if (__hip_atomic_fetch_add(&bar[256], 1u, __ATOMIC_ACQ_REL,
                                           __HIP_MEMORY_SCOPE_AGENT) == 7u) {
                    #pragma unroll
                    for (int l2 = 0; l2 < 8; ++l2)
                        __hip_atomic_store(&bar[l2 << 5], 0u, __ATOMIC_RELAXED,
                                           __HIP_MEMORY_SCOPE_AGENT);
                    __hip_atomic_store(&bar[256], 0u, __ATOMIC_RELAXED,
                                       __HIP_MEMORY_SCOPE_AGENT);
                    __hip_atomic_fetch_add(&bar[288], 1u, __ATOMIC_RELEASE,
                                           __HIP_MEMORY_SCOPE_AGENT);   // A_gen++
                }
            }
        }
        genA++;

        // ================= combine phase (blocks 0..63) =================
        if (is_cb) {
            if (tid == 0) {
                while (__hip_atomic_load(&bar[288], __ATOMIC_ACQUIRE,
                                         __HIP_MEMORY_SCOPE_AGENT) < genA)
                    __builtin_amdgcn_s_sleep(1);
            }
            __syncthreads();                 // A passed: P(t) visible

            const int bb = bid;
            const int i  = tid;
            float s[16];
            #pragma unroll
            for (int r = 0; r < 16; ++r) s[r] = 0.f;
            const float* Pp = P + bb * HID_ + i;
            #pragma unroll
            for (int cc = 0; cc < 128; cc += 16) {
                #pragma unroll
                for (int r = 0; r < 16; ++r) s[r] += Pp[(size_t)(cc + r) * 16384];
            }
            float h0 = ((s[0] + s[1]) + (s[2] + s[3])) + ((s[4] + s[5]) + (s[6] + s[7]));
            float h1 = ((s[8] + s[9]) + (s[10] + s[11])) + ((s[12] + s[13]) + (s[14] + s[15]));
            const float hidden = h0 + h1;

            float inp = bin;
            const float* ur = u + bb * (T_ * IN_) + t * IN_;
            #pragma unroll
            for (int k = 0; k < 64; ++k) inp += ur[k] * win[k];

            const float n  = noise[t * (B_ * HID_) + bb * HID_ + i];
            const float xn = 0.8f * xcur + 0.05f * n + 0.2f * (hidden + inp);
            xcur = xn;

            traj[(size_t)bb * (T_ * HID_) + t * HID_ + i] = xn;
            rB[bb * HID_ + i] = f2bf(tanhf(xn));
            if (t == T_ - 1) xf[bb * HID_ + i] = xn;

            __syncthreads();                 // all rB stores drained
            if (tid == 0) {
                __threadfence();             // release rB/traj
                if (__hip_atomic_fetch_add(&bar[320], 1u, __ATOMIC_ACQ_REL,
                                           __HIP_MEMORY_SCOPE_AGENT) == 63u) {
                    __hip_atomic_store(&bar[320], 0u, __ATOMIC_RELAXED,
                                       __HIP_MEMORY_SCOPE_AGENT);
                    __hip_atomic_fetch_add(&bar[352], 1u, __ATOMIC_RELEASE,
                                           __HIP_MEMORY_SCOPE_AGENT);   // B_gen++
                }
            }
        }
        genB++;

        // ================= all blocks wait for rB(t+1) =================
        if (tid == 0) {
            while (__hip_atomic_load(&bar[352], __ATOMIC_ACQUIRE,
                                     __HIP_MEMORY_SCOPE_AGENT) < genB)
                __builtin_amdgcn_s_sleep(1);
        }
        __syncthreads();
    }
}

// ---- output projection (fp32) --------------------------------------------
__global__ __launch_bounds__(256) void output_kernel(const float* __restrict__ traj,
                                                     const float* __restrict__ W_out,
                                                     const float* __restrict__ b_out,
                                                     float* __restrict__ out)
{
    __shared__ float r_s[16 * 256];
    __shared__ float Wt[64 * 65];

    const int tid = threadIdx.x;
    const int b   = blockIdx.x >> 5;
    const int t0  = (blockIdx.x & 31) << 4;

    #pragma unroll
    for (int r = 0; r < 16; ++r) {
        r_s[r * 256 + tid] = tanhf(traj[(size_t)b * (T_ * HID_) + (t0 + r) * HID_ + tid]);
    }

    const int o  = tid & 63;
    const int rg = tid >> 6;
    float acc0 = b_out[o];
    float acc1 = acc0, acc2 = acc0, acc3 = acc0;

    for (int ib = 0; ib < 4; ++ib) {
        __syncthreads();
        #pragma unroll
        for (int r = 0; r < 16; ++r) {
            const int f  = (r << 8) + tid;
            const int oo = f >> 6;
            const int il = f & 63;
            Wt[il * 65 + oo] = W_out[oo * 256 + (ib << 6) + il];
        }
        __syncthreads();
        #pragma unroll 16
        for (int il = 0; il < 64; ++il) {
            const float w = Wt[il * 65 + o];
            const int i = (ib << 6) + il;
            acc0 += r_s[(rg * 4 + 0) * 256 + i] * w;
            acc1 += r_s[(rg * 4 + 1) * 256 + i] * w;
            acc2 += r_s[(rg * 4 + 2) * 256 + i] * w;
            acc3 += r_s[(rg * 4 + 3) * 256 + i] * w;
        }
    }
    float* ob = out + b * (T_ * IN_) + (t0 + (rg << 2)) * IN_ + o;
    ob[0 * IN_] = acc0;
    ob[1 * IN_] = acc1;
    ob[2 * IN_] = acc2;
    ob[3 * IN_] = acc3;
}

extern "C" void kernel_launch(void* const* d_in, const int* in_sizes, int n_in,
                              void* d_out, int out_size, void* d_ws, size_t ws_size,
                              hipStream_t stream)
{
    const float* u     = (const float*)d_in[0];
    const float* x0    = (const float*)d_in[1];
    const float* noise = (const float*)d_in[2];
    const float* W_hh  = (const float*)d_in[3];
    const float* W_in  = (const float*)d_in[4];
    const float* b_in  = (const float*)d_in[5];
    const float* W_out = (const float*)d_in[6];
    const float* b_out = (const float*)d_in[7];

    float* out  = (float*)d_out;
    float* xf   = out + 2097152;            // [B][HID]
    float* traj = out + 2097152 + 16384;    // [B][T][HID]

    // ws layout (float offsets):
    //   P   : 0          (8 MB, 128 slices x 64 x 256)
    //   Wb  : 2,097,152  (32 MB bf16)
    //   rB  : 10,485,760 (16384 ushorts)
    //   bar : 10,493,952 (512 uints)
    float* ws = (float*)d_ws;
    float*          P   = ws;
    unsigned short* Wb  = (unsigned short*)(ws + 2097152);
    unsigned short* rB  = (unsigned short*)(ws + 10485760);
    unsigned int*   bar = (unsigned int*)(ws + 10493952);

    conv_w<<<16384, 256, 0, stream>>>(W_hh, Wb);
    init_rB<<<64, 256, 0, stream>>>(x0, rB, bar);
    rnn_persistent<<<512, 256, 0, stream>>>(Wb, rB, P, u, x0, noise,
                                            W_in, b_in, traj, xf, bar);
    output_kernel<<<2048, 256, 0, stream>>>(traj, W_out, b_out, out);
}

// Round 5
// 23662.921 us; speedup vs baseline: 6.9761x; 6.9761x over previous
//
#include <hip/hip_runtime.h>
#include <math.h>

#define B_   64
#define T_   512
#define IN_  64
#define HID_ 256
#define KTOT 65536   // HID*HID

typedef __attribute__((ext_vector_type(8))) short  short8;
typedef __attribute__((ext_vector_type(4))) float  floatx4;

__device__ __forceinline__ unsigned short f2bf(float f) {
    unsigned int u = __float_as_uint(f);
    u += 0x7FFFu + ((u >> 16) & 1u);          // round-to-nearest-even
    return (unsigned short)(u >> 16);
}
__device__ __forceinline__ float bf2f(unsigned short s) {
    return __uint_as_float(((unsigned int)s) << 16);
}

// coherence-point (agent-scope, cache-bypassing) accessors
__device__ __forceinline__ void cstore_f(float* p, float v) {
    __hip_atomic_store(p, v, __ATOMIC_RELAXED, __HIP_MEMORY_SCOPE_AGENT);
}
__device__ __forceinline__ float cload_f(const float* p) {
    return __hip_atomic_load((float*)p, __ATOMIC_RELAXED, __HIP_MEMORY_SCOPE_AGENT);
}
__device__ __forceinline__ void cstore_u(unsigned* p, unsigned v) {
    __hip_atomic_store(p, v, __ATOMIC_RELAXED, __HIP_MEMORY_SCOPE_AGENT);
}
__device__ __forceinline__ unsigned cload_u(const unsigned* p) {
    return __hip_atomic_load((unsigned*)p, __ATOMIC_RELAXED, __HIP_MEMORY_SCOPE_AGENT);
}
__device__ __forceinline__ unsigned cadd_u(unsigned* p) {
    return __hip_atomic_fetch_add(p, 1u, __ATOMIC_RELAXED, __HIP_MEMORY_SCOPE_AGENT);
}

// ---- once per launch: W_hh fp32 -> bf16 ----------------------------------
__global__ __launch_bounds__(256) void conv_w(const float* __restrict__ W,
                                              unsigned short* __restrict__ Wb)
{
    const size_t idx = ((size_t)blockIdx.x * 256 + threadIdx.x) * 4;
    const float4 v = *(const float4*)(W + idx);
    unsigned int lo = (unsigned int)f2bf(v.x) | ((unsigned int)f2bf(v.y) << 16);
    unsigned int hi = (unsigned int)f2bf(v.z) | ((unsigned int)f2bf(v.w) << 16);
    *(uint2*)(Wb + idx) = make_uint2(lo, hi);
}

// ---- init: rB(bf16) from x0 (coherent), zero barrier words ---------------
__global__ __launch_bounds__(256) void init_rB(const float* __restrict__ x0,
                                               unsigned short* __restrict__ rB,
                                               unsigned int* __restrict__ bar)
{
    const int b = blockIdx.x;
    const int i = threadIdx.x;
    // pack two bf16 per dword, coherent store (consumers read coherent)
    if ((i & 1) == 0) {
        unsigned short lo = f2bf(tanhf(x0[b * HID_ + i]));
        unsigned short hi = f2bf(tanhf(x0[b * HID_ + i + 1]));
        cstore_u((unsigned*)rB + b * 128 + (i >> 1),
                 (unsigned)lo | ((unsigned)hi << 16));
    }
    if (b == 0) { bar[i] = 0u; bar[i + 256] = 0u; bar[i + 512] = 0u; bar[i + 768] = 0u; }
}

// Barrier words (dword idx, 128B apart): A-leaf[l]=l*32 (l=0..7), A-root=256,
// A-gen=288, B-leaf[l]=512+l*32, B-root=768, B-gen=800. Monotone counters,
// never reset: step s complete when leaf hits 64*s (A) / 8*s (B).

// ---- persistent kernel: all 512 timesteps, fence-free grid barrier -------
// grid = 512 blocks x 256 thr, 64 KB static LDS, launch_bounds(256,2)
// => 2 blocks/CU, all 512 co-resident (proven in R4).
__global__ __launch_bounds__(256, 2) void rnn_persistent(
    const unsigned short* __restrict__ Wb,
    unsigned short* __restrict__ rB,
    float* __restrict__ P,
    const float* __restrict__ u,
    const float* __restrict__ x0,
    const float* __restrict__ noise,
    const float* __restrict__ W_in,
    const float* __restrict__ b_in,
    float* __restrict__ traj,
    float* __restrict__ xf,
    unsigned int* __restrict__ bar)
{
    __shared__ unsigned short A_lds[32768];  // 64 KB: [itile(4)][kc(16)][lane(64)][8]

    const int tid = threadIdx.x;
    const int l   = tid & 63;
    const int w   = tid >> 6;        // wave 0..3
    const int m   = l & 15;
    const int q   = l >> 4;
    const int bid = blockIdx.x;
    const int ig  = bid >> 7;        // i-group 0..3
    const int c   = bid & 127;       // k-slice 0..127
    const int i0  = ig << 6;

    // ---- stage W slice to LDS once (persists across all steps) ----
    {
        const unsigned short* src = Wb + (size_t)(i0 + (w << 4) + m) * KTOT
                                       + (c << 9) + (q << 3);
        unsigned short* dst = &A_lds[(w << 13) + (l << 3)];
        #pragma unroll
        for (int kc = 0; kc < 16; ++kc) {
            *(uint4*)(dst + (kc << 9)) = *(const uint4*)(src + (kc << 5));
        }
    }
    __syncthreads();

    const int b = (w << 4) + m;                  // gemm: this lane's batch row
    const unsigned* rB32 = (const unsigned*)rB;
    const unsigned* rrow32 = rB32 + b * 128 + (q << 2);

    // ---- combine-phase register state (blocks 0..63 only) ----
    const bool is_cb = (bid < 64);
    float win[64];
    float bin = 0.f, xcur = 0.f;
    if (is_cb) {
        #pragma unroll
        for (int k = 0; k < 64; ++k) win[k] = W_in[tid * IN_ + k];  // W_in[i][k]
        bin  = b_in[tid];
        xcur = x0[bid * HID_ + tid];
    }

    #pragma unroll 1
    for (int t = 0; t < T_; ++t) {
        const unsigned gen = (unsigned)(t + 1);

        // ================= gemm phase (all blocks) =================
        // preload this lane's rB data (coherence-point dword loads)
        const unsigned rjw = cload_u(rB32 + b * 128 + c);
        const float rj0 = bf2f((unsigned short)(rjw & 0xffffu));
        const float rj1 = bf2f((unsigned short)(rjw >> 16));
        unsigned rbuf[32];
        #pragma unroll
        for (int s = 0; s < 8; ++s) {
            #pragma unroll
            for (int d = 0; d < 4; ++d)
                rbuf[(s << 2) + d] = cload_u(&rrow32[(s << 4) + d]);
        }

        floatx4 acc0 = {0.f, 0.f, 0.f, 0.f};
        floatx4 acc1 = {0.f, 0.f, 0.f, 0.f};
        floatx4 acc2 = {0.f, 0.f, 0.f, 0.f};
        floatx4 acc3 = {0.f, 0.f, 0.f, 0.f};

        #pragma unroll
        for (int kc = 0; kc < 16; ++kc) {
            const float rj = (kc < 8) ? rj0 : rj1;
            const unsigned* rv = &rbuf[(kc & 7) << 2];
            short8 gfrag;
            {
                unsigned int* gp = (unsigned int*)&gfrag;
                #pragma unroll
                for (int p = 0; p < 4; ++p) {
                    const unsigned rw = rv[p];
                    const float lo = bf2f((unsigned short)(rw & 0xffffu)) * rj;
                    const float hi = bf2f((unsigned short)(rw >> 16))     * rj;
                    gp[p] = (unsigned int)f2bf(lo) | ((unsigned int)f2bf(hi) << 16);
                }
            }
            const unsigned short* ab = &A_lds[(kc << 9) + (l << 3)];
            const short8 w0 = *(const short8*)(ab);
            const short8 w1 = *(const short8*)(ab + 8192);
            const short8 w2 = *(const short8*)(ab + 16384);
            const short8 w3 = *(const short8*)(ab + 24576);
            acc0 = __builtin_amdgcn_mfma_f32_16x16x32_bf16(gfrag, w0, acc0, 0, 0, 0);
            acc1 = __builtin_amdgcn_mfma_f32_16x16x32_bf16(gfrag, w1, acc1, 0, 0, 0);
            acc2 = __builtin_amdgcn_mfma_f32_16x16x32_bf16(gfrag, w2, acc2, 0, 0, 0);
            acc3 = __builtin_amdgcn_mfma_f32_16x16x32_bf16(gfrag, w3, acc3, 0, 0, 0);
        }

        // C layout: row(b_local) = q*4+reg, col(i_local) = m  (coherent stores)
        #pragma unroll
        for (int reg = 0; reg < 4; ++reg) {
            float* dst = P + (c << 14) + ((w << 4) + (q << 2) + reg) * HID_ + i0 + m;
            cstore_f(dst + 0,  acc0[reg]);
            cstore_f(dst + 16, acc1[reg]);
            cstore_f(dst + 32, acc2[reg]);
            cstore_f(dst + 48, acc3[reg]);
        }

        __syncthreads();   // drains vmcnt(0): all block's P stores globally visible
        if (tid == 0) {
            if (cadd_u(&bar[(bid & 7) << 5]) + 1u == 64u * gen) {
                if (cadd_u(&bar[256]) + 1u == 8u * gen)
                    cadd_u(&bar[288]);                          // A_gen++
            }
        }

        // ================= combine phase (blocks 0..63) =================
        if (is_cb) {
            if (tid == 0) {
                while (cload_u(&bar[288]) < gen)
                    __builtin_amdgcn_s_sleep(1);
            }
            __syncthreads();                 // A passed: P(t) globally visible

            const int bb = bid;
            const int i  = tid;
            float s[16];
            #pragma unroll
            for (int r = 0; r < 16; ++r) s[r] = 0.f;
            const float* Pp = P + bb * HID_ + i;
            #pragma unroll
            for (int cc = 0; cc < 128; cc += 16) {
                #pragma unroll
                for (int r = 0; r < 16; ++r)
                    s[r] += cload_f(Pp + (size_t)(cc + r) * 16384);
            }
            float h0 = ((s[0] + s[1]) + (s[2] + s[3])) + ((s[4] + s[5]) + (s[6] + s[7]));
            float h1 = ((s[8] + s[9]) + (s[10] + s[11])) + ((s[12] + s[13]) + (s[14] + s[15]));
            const float hidden = h0 + h1;

            float inp = bin;
            const float* ur = u + bb * (T_ * IN_) + t * IN_;
            #pragma unroll
            for (int k = 0; k < 64; ++k) inp += ur[k] * win[k];

            const float n  = noise[t * (B_ * HID_) + bb * HID_ + i];
            const float xn = 0.8f * xcur + 0.05f * n + 0.2f * (hidden + inp);
            xcur = xn;

            traj[(size_t)bb * (T_ * HID_) + t * HID_ + i] = xn;   // normal store (next dispatch reads)
            // rB: pack pair, coherent dword store
            {
                const unsigned rv16 = (unsigned)f2bf(tanhf(xn));
                const unsigned other = __shfl_xor(rv16, 1, 64);
                if ((i & 1) == 0)
                    cstore_u((unsigned*)rB + bb * 128 + (i >> 1),
                             rv16 | (other << 16));
            }
            if (t == T_ - 1) xf[bb * HID_ + tid] = xn;

            __syncthreads();   // drains vmcnt(0): rB stores globally visible
            if (tid == 0) {
                if (cadd_u(&bar[512 + ((bid & 7) << 5)]) + 1u == 8u * gen) {
                    if (cadd_u(&bar[768]) + 1u == 8u * gen)
                        cadd_u(&bar[800]);                      // B_gen++
                }
            }
        }

        // ================= all blocks wait for rB(t+1) =================
        if (tid == 0) {
            while (cload_u(&bar[800]) < gen)
                __builtin_amdgcn_s_sleep(1);
        }
        __syncthreads();
    }
}

// ---- output projection (fp32) --------------------------------------------
__global__ __launch_bounds__(256) void output_kernel(const float* __restrict__ traj,
                                                     const float* __restrict__ W_out,
                                                     const float* __restrict__ b_out,
                                                     float* __restrict__ out)
{
    __shared__ float r_s[16 * 256];
    __shared__ float Wt[64 * 65];

    const int tid = threadIdx.x;
    const int b   = blockIdx.x >> 5;
    const int t0  = (blockIdx.x & 31) << 4;

    #pragma unroll
    for (int r = 0; r < 16; ++r) {
        r_s[r * 256 + tid] = tanhf(traj[(size_t)b * (T_ * HID_) + (t0 + r) * HID_ + tid]);
    }

    const int o  = tid & 63;
    const int rg = tid >> 6;
    float acc0 = b_out[o];
    float acc1 = acc0, acc2 = acc0, acc3 = acc0;

    for (int ib = 0; ib < 4; ++ib) {
        __syncthreads();
        #pragma unroll
        for (int r = 0; r < 16; ++r) {
            const int f  = (r << 8) + tid;
            const int oo = f >> 6;
            const int il = f & 63;
            Wt[il * 65 + oo] = W_out[oo * 256 + (ib << 6) + il];
        }
        __syncthreads();
        #pragma unroll 16
        for (int il = 0; il < 64; ++il) {
            const float w = Wt[il * 65 + o];
            const int i = (ib << 6) + il;
            acc0 += r_s[(rg * 4 + 0) * 256 + i] * w;
            acc1 += r_s[(rg * 4 + 1) * 256 + i] * w;
            acc2 += r_s[(rg * 4 + 2) * 256 + i] * w;
            acc3 += r_s[(rg * 4 + 3) * 256 + i] * w;
        }
    }
    float* ob = out + b * (T_ * IN_) + (t0 + (rg << 2)) * IN_ + o;
    ob[0 * IN_] = acc0;
    ob[1 * IN_] = acc1;
    ob[2 * IN_] = acc2;
    ob[3 * IN_] = acc3;
}

extern "C" void kernel_launch(void* const* d_in, const int* in_sizes, int n_in,
                              void* d_out, int out_size, void* d_ws, size_t ws_size,
                              hipStream_t stream)
{
    const float* u     = (const float*)d_in[0];
    const float* x0    = (const float*)d_in[1];
    const float* noise = (const float*)d_in[2];
    const float* W_hh  = (const float*)d_in[3];
    const float* W_in  = (const float*)d_in[4];
    const float* b_in  = (const float*)d_in[5];
    const float* W_out = (const float*)d_in[6];
    const float* b_out = (const float*)d_in[7];

    float* out  = (float*)d_out;
    float* xf   = out + 2097152;            // [B][HID]
    float* traj = out + 2097152 + 16384;    // [B][T][HID]

    // ws layout (float offsets):
    //   P   : 0          (8 MB, 128 slices x 64 x 256)
    //   Wb  : 2,097,152  (32 MB bf16)
    //   rB  : 10,485,760 (16384 ushorts)
    //   bar : 10,493,952 (1024 uints)
    float* ws = (float*)d_ws;
    float*          P   = ws;
    unsigned short* Wb  = (unsigned short*)(ws + 2097152);
    unsigned short* rB  = (unsigned short*)(ws + 10485760);
    unsigned int*   bar = (unsigned int*)(ws + 10493952);

    conv_w<<<16384, 256, 0, stream>>>(W_hh, Wb);
    init_rB<<<64, 256, 0, stream>>>(x0, rB, bar);
    rnn_persistent<<<512, 256, 0, stream>>>(Wb, rB, P, u, x0, noise,
                                            W_in, b_in, traj, xf, bar);
    output_kernel<<<2048, 256, 0, stream>>>(traj, W_out, b_out, out);
}